// Round 3
// baseline (104.151 us; speedup 1.0000x reference)
//
#include <hip/hip_runtime.h>

// Problem constants (from reference)
#define Bsz  32
#define Nn   512
#define DIN  256
#define DSC  32
#define Cc   48
#define Hh   152
#define Ww   160
#define HW   (Hh * Ww)        // 24320
#define COUT (Cc + DSC)       // 80
#define TILE 256              // cells per gather tile; HW/TILE = 95 exactly
#define TPB  95               // gather tiles per batch
#define NGB  (Bsz * TPB)      // 3040 gather blocks
#define NCB  (Bsz * Cc * 2)   // 3072 copy blocks (half-plane each)

// ---------------------------------------------------------------------------
// K1: proj = relu(emb @ W + b) * mask -> projws [B*N, DSC] (2 MB, L2-resident)
//     flat cell index per entity -> idxws [B*N]
// ---------------------------------------------------------------------------
__global__ __launch_bounds__(256) void proj_kernel(
    const float* __restrict__ emb, const float* __restrict__ mask,
    const int* __restrict__ loc, const float* __restrict__ Wp,
    const float* __restrict__ bp, float* __restrict__ projws,
    int* __restrict__ idxws) {

    __shared__ float Ws[DIN][DSC];        // 32 KB
    __shared__ float Es[32][DIN + 4];     // 32.5 KB, +4 pad for bank spread

    const int tid  = threadIdx.x;
    const int ent0 = blockIdx.x * 32;

    for (int i = tid; i < (DIN * DSC) / 4; i += 256)
        ((float4*)Ws)[i] = ((const float4*)Wp)[i];
    for (int i = tid; i < (32 * DIN) / 4; i += 256) {
        const int e  = i >> 6;
        const int k4 = i & 63;
        *(float4*)&Es[e][k4 * 4] =
            ((const float4*)(emb + (size_t)(ent0 + e) * DIN))[k4];
    }
    __syncthreads();

    const int g   = tid >> 3;             // entity within block
    const int dq  = (tid & 7) * 4;        // first of 4 output channels
    const int ent = ent0 + g;

    float ax = bp[dq + 0], ay = bp[dq + 1], az = bp[dq + 2], aw = bp[dq + 3];

    #pragma unroll 4
    for (int k = 0; k < DIN; k += 4) {
        const float4 ev = *(const float4*)&Es[g][k];
        const float4 w0 = *(const float4*)&Ws[k + 0][dq];
        const float4 w1 = *(const float4*)&Ws[k + 1][dq];
        const float4 w2 = *(const float4*)&Ws[k + 2][dq];
        const float4 w3 = *(const float4*)&Ws[k + 3][dq];
        ax = fmaf(ev.x, w0.x, fmaf(ev.y, w1.x, fmaf(ev.z, w2.x, fmaf(ev.w, w3.x, ax))));
        ay = fmaf(ev.x, w0.y, fmaf(ev.y, w1.y, fmaf(ev.z, w2.y, fmaf(ev.w, w3.y, ay))));
        az = fmaf(ev.x, w0.z, fmaf(ev.y, w1.z, fmaf(ev.z, w2.z, fmaf(ev.w, w3.z, az))));
        aw = fmaf(ev.x, w0.w, fmaf(ev.y, w1.w, fmaf(ev.z, w2.w, fmaf(ev.w, w3.w, aw))));
    }

    const float m = mask[ent];
    float4 r;
    r.x = fmaxf(ax, 0.f) * m;
    r.y = fmaxf(ay, 0.f) * m;
    r.z = fmaxf(az, 0.f) * m;
    r.w = fmaxf(aw, 0.f) * m;
    ((float4*)projws)[(size_t)ent * (DSC / 4) + (tid & 7)] = r;

    if ((tid & 7) == 0) {
        int y = loc[2 * ent + 0];
        int x = loc[2 * ent + 1];
        y = min(max(y, 0), Hh - 1);
        x = min(max(x, 0), Ww - 1);
        idxws[ent] = y * Ww + x;
    }
}

// ---------------------------------------------------------------------------
// K2: fused output assembly, copy/gather blocks interleaved (even/odd bid).
//  copy block (cid):   copy half a spatial plane -> out channels [0,48)
//  gather block (gid): one (b, 256-cell tile) x 32 channels, accumulator in
//    REGISTERS (thread = 4 cells x 8 channels = 8 float4). Scan 512 entity
//    indices, stage matched proj rows (<=32 at a time) in 4 KB LDS, add via
//    compile-time-component switch, stream out as full float4 lines.
//  LDS ~6.2 KB -> occupancy wave-capped, not LDS-capped.
// ---------------------------------------------------------------------------
__global__ __launch_bounds__(256) void fused_out_kernel(
    const float* __restrict__ spatial, const float* __restrict__ projws,
    const int* __restrict__ idxws, float* __restrict__ out) {

    __shared__ int   mlist[Nn];           // 2 KB: (r<<16)|entity
    __shared__ float pbuf[32][DSC];       // 4 KB: staged proj rows
    __shared__ int   mcount;

    const int bid = blockIdx.x;
    const int tid = threadIdx.x;

    int cid = -1, gid = -1;
    if (bid < 2 * NGB) { if (bid & 1) gid = bid >> 1; else cid = bid >> 1; }
    else                cid = NGB + (bid - 2 * NGB);

    if (cid >= 0) {                       // ---- copy half-plane ----
        const int plane = cid >> 1;       // b*Cc + c
        const int half  = cid & 1;
        const int b = plane / Cc, c = plane % Cc;
        const float4* src = (const float4*)(spatial + (size_t)plane * HW + half * (HW / 2));
        float4*       dst = (float4*)(out + ((size_t)(b * COUT + c)) * HW + half * (HW / 2));
        for (int i = tid; i < (HW / 2) / 4; i += 256) dst[i] = src[i];
        return;
    }

    // ---- gather tile ----
    const int b  = gid / TPB;
    const int t0 = (gid % TPB) * TILE;

    if (tid == 0) mcount = 0;
    __syncthreads();
    {
        const int2 v = ((const int2*)(idxws + b * Nn))[tid];  // entities 2t, 2t+1
        const int r0 = v.x - t0, r1 = v.y - t0;
        if ((unsigned)r0 < (unsigned)TILE) {
            const int p = atomicAdd(&mcount, 1);
            mlist[p] = (r0 << 16) | (2 * tid);
        }
        if ((unsigned)r1 < (unsigned)TILE) {
            const int p = atomicAdd(&mcount, 1);
            mlist[p] = (r1 << 16) | (2 * tid + 1);
        }
    }
    __syncthreads();

    const int cg  = tid & 63;             // cells 4cg .. 4cg+3
    const int ch0 = (tid >> 6) * 8;       // channels ch0 .. ch0+7
    float4 acc[8];
    #pragma unroll
    for (int j = 0; j < 8; ++j) acc[j] = make_float4(0.f, 0.f, 0.f, 0.f);

    const int M = mcount;
    for (int m0 = 0; m0 < M; m0 += 32) {
        const int nm = min(32, M - m0);
        if (tid < nm * 8) {
            const int m   = tid >> 3;
            const int ent = mlist[m0 + m] & 0xFFFF;
            ((float4*)pbuf[m])[tid & 7] =
                ((const float4*)(projws + ((size_t)b * Nn + ent) * DSC))[tid & 7];
        }
        __syncthreads();
        for (int mm = 0; mm < nm; ++mm) {
            const int rk = mlist[m0 + mm] >> 16;
            if ((rk >> 2) == cg) {
                const float4 f0 = *(const float4*)&pbuf[mm][ch0];
                const float4 f1 = *(const float4*)&pbuf[mm][ch0 + 4];
                switch (rk & 3) {
                case 0:
                    acc[0].x += f0.x; acc[1].x += f0.y; acc[2].x += f0.z; acc[3].x += f0.w;
                    acc[4].x += f1.x; acc[5].x += f1.y; acc[6].x += f1.z; acc[7].x += f1.w;
                    break;
                case 1:
                    acc[0].y += f0.x; acc[1].y += f0.y; acc[2].y += f0.z; acc[3].y += f0.w;
                    acc[4].y += f1.x; acc[5].y += f1.y; acc[6].y += f1.z; acc[7].y += f1.w;
                    break;
                case 2:
                    acc[0].z += f0.x; acc[1].z += f0.y; acc[2].z += f0.z; acc[3].z += f0.w;
                    acc[4].z += f1.x; acc[5].z += f1.y; acc[6].z += f1.z; acc[7].z += f1.w;
                    break;
                default:
                    acc[0].w += f0.x; acc[1].w += f0.y; acc[2].w += f0.z; acc[3].w += f0.w;
                    acc[4].w += f1.x; acc[5].w += f1.y; acc[6].w += f1.z; acc[7].w += f1.w;
                    break;
                }
            }
        }
        __syncthreads();
    }

    float* obase = out + ((size_t)b * COUT + Cc) * HW + t0 + 4 * cg;
    #pragma unroll
    for (int j = 0; j < 8; ++j)
        *(float4*)(obase + (size_t)(ch0 + j) * HW) = acc[j];
}

// ---------------------------------------------------------------------------
// Fallback path (only if ws_size too small): R1 design.
// ---------------------------------------------------------------------------
__global__ __launch_bounds__(256) void init_out_kernel(
    const float* __restrict__ spatial, float* __restrict__ out) {
    const int plane = blockIdx.x;
    const int b = plane / COUT;
    const int c = plane % COUT;
    float4* dst = (float4*)(out + (size_t)plane * HW);
    if (c < Cc) {
        const float4* src = (const float4*)(spatial + ((size_t)b * Cc + c) * HW);
        for (int i = threadIdx.x; i < HW / 4; i += blockDim.x) dst[i] = src[i];
    } else {
        const float4 z = make_float4(0.f, 0.f, 0.f, 0.f);
        for (int i = threadIdx.x; i < HW / 4; i += blockDim.x) dst[i] = z;
    }
}

__global__ __launch_bounds__(256) void scatter_kernel(
    const float* __restrict__ emb, const float* __restrict__ mask,
    const int* __restrict__ loc, const float* __restrict__ Wp,
    const float* __restrict__ bp, float* __restrict__ out) {

    __shared__ float Ws[DIN][DSC];
    __shared__ float Es[32][DIN + 4];

    const int tid  = threadIdx.x;
    const int ent0 = blockIdx.x * 32;

    for (int i = tid; i < (DIN * DSC) / 4; i += 256)
        ((float4*)Ws)[i] = ((const float4*)Wp)[i];
    for (int i = tid; i < (32 * DIN) / 4; i += 256) {
        const int e  = i >> 6;
        const int k4 = i & 63;
        *(float4*)&Es[e][k4 * 4] =
            ((const float4*)(emb + (size_t)(ent0 + e) * DIN))[k4];
    }
    __syncthreads();

    const int g   = tid >> 3;
    const int dq  = (tid & 7) * 4;
    const int ent = ent0 + g;
    const int b   = ent >> 9;

    float ax = bp[dq + 0], ay = bp[dq + 1], az = bp[dq + 2], aw = bp[dq + 3];

    #pragma unroll 4
    for (int k = 0; k < DIN; k += 4) {
        const float4 ev = *(const float4*)&Es[g][k];
        const float4 w0 = *(const float4*)&Ws[k + 0][dq];
        const float4 w1 = *(const float4*)&Ws[k + 1][dq];
        const float4 w2 = *(const float4*)&Ws[k + 2][dq];
        const float4 w3 = *(const float4*)&Ws[k + 3][dq];
        ax = fmaf(ev.x, w0.x, fmaf(ev.y, w1.x, fmaf(ev.z, w2.x, fmaf(ev.w, w3.x, ax))));
        ay = fmaf(ev.x, w0.y, fmaf(ev.y, w1.y, fmaf(ev.z, w2.y, fmaf(ev.w, w3.y, ay))));
        az = fmaf(ev.x, w0.z, fmaf(ev.y, w1.z, fmaf(ev.z, w2.z, fmaf(ev.w, w3.z, az))));
        aw = fmaf(ev.x, w0.w, fmaf(ev.y, w1.w, fmaf(ev.z, w2.w, fmaf(ev.w, w3.w, aw))));
    }

    const float m = mask[ent];
    int y = loc[2 * ent + 0];
    int x = loc[2 * ent + 1];
    y = min(max(y, 0), Hh - 1);
    x = min(max(x, 0), Ww - 1);

    float* dst = out + ((size_t)b * COUT + Cc) * HW + (size_t)y * Ww + x;
    float v[4] = { ax, ay, az, aw };
    #pragma unroll
    for (int j = 0; j < 4; ++j) {
        const float r = fmaxf(v[j], 0.f) * m;
        if (r != 0.f)
            atomicAdd(dst + (size_t)(dq + j) * HW, r);
    }
}

// ---------------------------------------------------------------------------
extern "C" void kernel_launch(void* const* d_in, const int* in_sizes, int n_in,
                              void* d_out, int out_size, void* d_ws, size_t ws_size,
                              hipStream_t stream) {
    const float* spatial = (const float*)d_in[0];  // [B, C, H, W]
    const float* emb     = (const float*)d_in[1];  // [B, N, DIN]
    const float* mask    = (const float*)d_in[2];  // [B, N]
    const int*   loc     = (const int*)d_in[3];    // [B, N, 2]
    const float* Wp      = (const float*)d_in[4];  // [DIN, DSC]
    const float* bp      = (const float*)d_in[5];  // [DSC]
    float* out = (float*)d_out;                    // [B, COUT, H, W]

    const size_t need = (size_t)Bsz * Nn * DSC * sizeof(float)
                      + (size_t)Bsz * Nn * sizeof(int);
    if (ws_size >= need) {
        float* projws = (float*)d_ws;
        int*   idxws  = (int*)((char*)d_ws + (size_t)Bsz * Nn * DSC * sizeof(float));
        proj_kernel<<<(Bsz * Nn) / 32, 256, 0, stream>>>(emb, mask, loc, Wp, bp,
                                                         projws, idxws);
        fused_out_kernel<<<NCB + NGB, 256, 0, stream>>>(spatial, projws, idxws, out);
    } else {
        init_out_kernel<<<Bsz * COUT, 256, 0, stream>>>(spatial, out);
        scatter_kernel<<<(Bsz * Nn) / 32, 256, 0, stream>>>(emb, mask, loc, Wp, bp, out);
    }
}